// Round 1
// baseline (501.487 us; speedup 1.0000x reference)
//
#include <hip/hip_runtime.h>
#include <hip/hip_bf16.h>
#include <cstdint>
#include <cstddef>

// ---------------- problem constants ----------------
#define M_TOK 4096          // B*S = 4*1024 tokens
#define HID   1024
#define NHEAD 16002
#define NHEAD_PAD 16128     // 126*128
#define P0    256
#define N0    12000
#define N0_PAD 12032        // 94*128
#define P1    64
#define P1_PAD 128
#define N1    8000
#define N1_PAD 8064         // 63*128

typedef __bf16 bf16_t;
typedef __bf16 bf16x8 __attribute__((ext_vector_type(8)));
typedef __bf16 bf16x4 __attribute__((ext_vector_type(4)));
typedef float  f32x4  __attribute__((ext_vector_type(4)));

// ---------------- cast inp f32 -> bf16 (vectorized x4) ----------------
__global__ void cast_kernel(const float* __restrict__ src, bf16_t* __restrict__ dst, int n4) {
    int i = blockIdx.x * blockDim.x + threadIdx.x;
    if (i < n4) {
        float4 v = reinterpret_cast<const float4*>(src)[i];
        bf16x4 o;
        o[0] = (bf16_t)v.x; o[1] = (bf16_t)v.y; o[2] = (bf16_t)v.z; o[3] = (bf16_t)v.w;
        reinterpret_cast<bf16x4*>(dst)[i] = o;
    }
}

// ---------------- tiled transpose with zero padding ----------------
// src: K x N (f32, row-major).  dst: Npad x Kpad (bf16, row-major), pad = 0.
__global__ void transpose_pad(const float* __restrict__ W, bf16_t* __restrict__ WT,
                              int K, int N, int Kpad, int Npad) {
    __shared__ float tile[32][33];
    int n0 = blockIdx.x * 32, k0 = blockIdx.y * 32;
    int tx = threadIdx.x & 31, ty = threadIdx.x >> 5;   // 32 x 8
    #pragma unroll
    for (int i = 0; i < 32; i += 8) {
        int k = k0 + ty + i, n = n0 + tx;
        tile[ty + i][tx] = (k < K && n < N) ? W[(size_t)k * N + n] : 0.0f;
    }
    __syncthreads();
    #pragma unroll
    for (int i = 0; i < 32; i += 8) {
        int n = n0 + ty + i, k = k0 + tx;
        if (n < Npad && k < Kpad)
            WT[(size_t)n * Kpad + k] = (bf16_t)tile[tx][ty + i];
    }
}

// ---------------- init: zero accumulators + out, precompute targets ----------------
// acc6: [sumH, labH, sum0, lab0, sum1, lab1] each 4096 f32.  tgts: 3*4096 int.
__global__ void init_kernel(const int* __restrict__ labels, float* __restrict__ acc6,
                            int* __restrict__ tgts, float* __restrict__ out) {
    int t = blockIdx.x * blockDim.x + threadIdx.x;   // 4096 threads
    for (int j = t; j < 6 * M_TOK; j += M_TOK) acc6[j] = 0.0f;
    if (t == 0) out[0] = 0.0f;
    int lbl = labels[t];
    tgts[t]             = (lbl < 16000) ? lbl : ((lbl < 28000) ? 16000 : 16001);
    int t0 = lbl - 16000; t0 = t0 < 0 ? 0 : (t0 > 11999 ? 11999 : t0);
    int t1 = lbl - 28000; t1 = t1 < 0 ? 0 : (t1 > 7999  ? 7999  : t1);
    tgts[M_TOK + t]     = t0;
    tgts[2 * M_TOK + t] = t1;
}

// ---------------- MFMA GEMM: C = A(M x K) * BT(Npad x K)^T ----------------
// Block tile 128x128, BK=32, 4 waves in 2x2, each wave 64x64 via 4x4 mfma_f32_16x16x32_bf16.
// LSE epilogue: sumexp += exp(logit) per token (masked col<realN), capture label logit.
// STORE epilogue: out[tok*Npad+col] = bf16(acc + bias) (bias masked to 0 for col>=realN).
template <bool LSE>
__launch_bounds__(256, 2)
__global__ void gemm_kernel(const bf16_t* __restrict__ A, const bf16_t* __restrict__ BT,
                            const float* __restrict__ bias, int K, int Npad, int realN,
                            const int* __restrict__ tgt, float* __restrict__ sumexp,
                            float* __restrict__ lab, bf16_t* __restrict__ out) {
    __shared__ __align__(16) bf16_t As[128][32];
    __shared__ __align__(16) bf16_t Bs[128][32];

    const int tid  = threadIdx.x;
    const int lane = tid & 63;
    const int wave = tid >> 6;
    const int wm = wave >> 1, wn = wave & 1;
    const int q = lane >> 4, lrow = lane & 15;
    const int m0 = blockIdx.x * 128, n0 = blockIdx.y * 128;

    f32x4 acc[4][4];
    #pragma unroll
    for (int mt = 0; mt < 4; mt++)
        #pragma unroll
        for (int nt = 0; nt < 4; nt++)
            acc[mt][nt] = (f32x4)(0.0f);

    for (int k0 = 0; k0 < K; k0 += 32) {
        #pragma unroll
        for (int p = 0; p < 2; p++) {
            int c = tid + p * 256;          // 512 chunks of 8 bf16
            int row = c >> 2, ko = (c & 3) * 8;
            *reinterpret_cast<bf16x8*>(&As[row][ko]) =
                *reinterpret_cast<const bf16x8*>(A + (size_t)(m0 + row) * K + k0 + ko);
            *reinterpret_cast<bf16x8*>(&Bs[row][ko]) =
                *reinterpret_cast<const bf16x8*>(BT + (size_t)(n0 + row) * K + k0 + ko);
        }
        __syncthreads();
        bf16x8 af[4], bfr[4];
        #pragma unroll
        for (int t = 0; t < 4; t++) {
            af[t]  = *reinterpret_cast<const bf16x8*>(&As[wm * 64 + t * 16 + lrow][q * 8]);
            bfr[t] = *reinterpret_cast<const bf16x8*>(&Bs[wn * 64 + t * 16 + lrow][q * 8]);
        }
        #pragma unroll
        for (int mt = 0; mt < 4; mt++)
            #pragma unroll
            for (int nt = 0; nt < 4; nt++)
                acc[mt][nt] = __builtin_amdgcn_mfma_f32_16x16x32_bf16(af[mt], bfr[nt], acc[mt][nt], 0, 0, 0);
        __syncthreads();
    }

    int colg[4]; float bias_v[4];
    #pragma unroll
    for (int nt = 0; nt < 4; nt++) {
        colg[nt] = n0 + wn * 64 + nt * 16 + lrow;
        bias_v[nt] = (colg[nt] < realN) ? bias[colg[nt]] : 0.0f;
    }

    if constexpr (LSE) {
        #pragma unroll
        for (int mt = 0; mt < 4; mt++) {
            int rowb = m0 + wm * 64 + mt * 16 + q * 4;
            #pragma unroll
            for (int r = 0; r < 4; r++) {
                int tok = rowb + r;
                int tg  = tgt[tok];
                float s = 0.0f;
                #pragma unroll
                for (int nt = 0; nt < 4; nt++) {
                    if (colg[nt] < realN) {
                        float logit = acc[mt][nt][r] + bias_v[nt];
                        s += __expf(logit);
                        if (colg[nt] == tg) atomicAdd(&lab[tok], logit);
                    }
                }
                s += __shfl_xor(s, 1);
                s += __shfl_xor(s, 2);
                s += __shfl_xor(s, 4);
                s += __shfl_xor(s, 8);
                if (lrow == 0) atomicAdd(&sumexp[tok], s);
            }
        }
    } else {
        #pragma unroll
        for (int mt = 0; mt < 4; mt++) {
            int rowb = m0 + wm * 64 + mt * 16 + q * 4;
            #pragma unroll
            for (int r = 0; r < 4; r++) {
                int tok = rowb + r;
                #pragma unroll
                for (int nt = 0; nt < 4; nt++)
                    out[(size_t)tok * Npad + colg[nt]] = (bf16_t)(acc[mt][nt][r] + bias_v[nt]);
            }
        }
    }
}

// ---------------- finalize: per-token loss, mask, mean ----------------
__global__ void finalize_kernel(const int* __restrict__ labels, const float* __restrict__ acc6,
                                float* __restrict__ out) {
    int t = blockIdx.x * blockDim.x + threadIdx.x;   // 4096 threads
    const float* sumH = acc6;
    const float* labH = acc6 + M_TOK;
    const float* sum0 = acc6 + 2 * M_TOK;
    const float* lab0 = acc6 + 3 * M_TOK;
    const float* sum1 = acc6 + 4 * M_TOK;
    const float* lab1 = acc6 + 5 * M_TOK;
    int lbl = labels[t];
    float l = 0.0f;
    if (lbl != 0) {
        l = logf(sumH[t]) - labH[t];
        if (lbl >= 16000 && lbl < 28000) l += logf(sum0[t]) - lab0[t];
        else if (lbl >= 28000)           l += logf(sum1[t]) - lab1[t];
    }
    l *= (1.0f / (float)M_TOK);
    #pragma unroll
    for (int off = 1; off < 64; off <<= 1) l += __shfl_xor(l, off);
    __shared__ float red[4];
    if ((threadIdx.x & 63) == 0) red[threadIdx.x >> 6] = l;
    __syncthreads();
    if (threadIdx.x == 0) atomicAdd(out, red[0] + red[1] + red[2] + red[3]);
}

// ---------------- host launcher ----------------
extern "C" void kernel_launch(void* const* d_in, const int* in_sizes, int n_in,
                              void* d_out, int out_size, void* d_ws, size_t ws_size,
                              hipStream_t stream) {
    const float* inp    = (const float*)d_in[0];
    const int*   labels = (const int*)  d_in[1];
    const float* head_W = (const float*)d_in[2];
    const float* head_b = (const float*)d_in[3];
    const float* t0_pW  = (const float*)d_in[4];
    const float* t0_pb  = (const float*)d_in[5];
    const float* t0_W   = (const float*)d_in[6];
    const float* t0_b   = (const float*)d_in[7];
    const float* t1_pW  = (const float*)d_in[8];
    const float* t1_pb  = (const float*)d_in[9];
    const float* t1_W   = (const float*)d_in[10];
    const float* t1_b   = (const float*)d_in[11];
    float* out = (float*)d_out;

    char* ws = (char*)d_ws;
    size_t off = 0;
    auto alloc = [&](size_t bytes) { char* p = ws + off; off += (bytes + 255) & ~(size_t)255; return p; };
    bf16_t* inp_bf = (bf16_t*)alloc((size_t)M_TOK * HID * 2);
    bf16_t* headWT = (bf16_t*)alloc((size_t)NHEAD_PAD * HID * 2);
    bf16_t* p0WT   = (bf16_t*)alloc((size_t)P0 * HID * 2);
    bf16_t* p1WT   = (bf16_t*)alloc((size_t)P1_PAD * HID * 2);
    bf16_t* t0WT   = (bf16_t*)alloc((size_t)N0_PAD * P0 * 2);
    bf16_t* t1WT   = (bf16_t*)alloc((size_t)N1_PAD * P1_PAD * 2);
    bf16_t* proj0  = (bf16_t*)alloc((size_t)M_TOK * P0 * 2);
    bf16_t* proj1  = (bf16_t*)alloc((size_t)M_TOK * P1_PAD * 2);
    float*  acc6   = (float*) alloc(6 * M_TOK * 4);
    int*    tgts   = (int*)   alloc(3 * M_TOK * 4);

    // stage 1: conversions / transposes
    cast_kernel<<<(M_TOK * HID / 4 + 255) / 256, 256, 0, stream>>>(inp, inp_bf, M_TOK * HID / 4);
    transpose_pad<<<dim3(NHEAD_PAD / 32, HID / 32), 256, 0, stream>>>(head_W, headWT, HID, NHEAD, HID, NHEAD_PAD);
    transpose_pad<<<dim3(P0 / 32,        HID / 32), 256, 0, stream>>>(t0_pW,  p0WT,   HID, P0,    HID, P0);
    transpose_pad<<<dim3(P1_PAD / 32,    HID / 32), 256, 0, stream>>>(t1_pW,  p1WT,   HID, P1,    HID, P1_PAD);
    transpose_pad<<<dim3(N0_PAD / 32,    P0 / 32),  256, 0, stream>>>(t0_W,   t0WT,   P0,  N0,    P0,  N0_PAD);
    transpose_pad<<<dim3(N1_PAD / 32,  P1_PAD / 32),256, 0, stream>>>(t1_W,   t1WT,   P1,  N1,  P1_PAD, N1_PAD);
    init_kernel<<<M_TOK / 256, 256, 0, stream>>>(labels, acc6, tgts, out);

    // stage 2: tail projections (store epilogue)
    gemm_kernel<false><<<dim3(M_TOK / 128, P0 / 128),     256, 0, stream>>>(inp_bf, p0WT, t0_pb, HID, P0,     P0, nullptr, nullptr, nullptr, proj0);
    gemm_kernel<false><<<dim3(M_TOK / 128, P1_PAD / 128), 256, 0, stream>>>(inp_bf, p1WT, t1_pb, HID, P1_PAD, P1, nullptr, nullptr, nullptr, proj1);

    // stage 3: logsumexp GEMMs (head + tails)
    gemm_kernel<true><<<dim3(M_TOK / 128, NHEAD_PAD / 128), 256, 0, stream>>>(inp_bf, headWT, head_b, HID,    NHEAD_PAD, NHEAD, tgts,             acc6,             acc6 + M_TOK,     nullptr);
    gemm_kernel<true><<<dim3(M_TOK / 128, N0_PAD / 128),    256, 0, stream>>>(proj0,  t0WT,   t0_b,   P0,     N0_PAD,    N0,    tgts + M_TOK,     acc6 + 2 * M_TOK, acc6 + 3 * M_TOK, nullptr);
    gemm_kernel<true><<<dim3(M_TOK / 128, N1_PAD / 128),    256, 0, stream>>>(proj1,  t1WT,   t1_b,   P1_PAD, N1_PAD,    N1,    tgts + 2 * M_TOK, acc6 + 4 * M_TOK, acc6 + 5 * M_TOK, nullptr);

    // stage 4: reduce to scalar mean
    finalize_kernel<<<M_TOK / 256, 256, 0, stream>>>(labels, acc6, out);
}

// Round 2
// 490.377 us; speedup vs baseline: 1.0227x; 1.0227x over previous
//
#include <hip/hip_runtime.h>
#include <hip/hip_bf16.h>
#include <cstdint>
#include <cstddef>

// ---------------- problem constants ----------------
#define M_TOK 4096          // B*S = 4*1024 tokens
#define HID   1024
#define NHEAD 16002
#define NHEAD_PAD 16128     // 126*128
#define P0    256
#define N0    12000
#define N0_PAD 12032        // 94*128
#define P1    64
#define P1_PAD 128
#define N1    8000
#define N1_PAD 8064         // 63*128

typedef __bf16 bf16_t;
typedef __bf16 bf16x8 __attribute__((ext_vector_type(8)));
typedef __bf16 bf16x4 __attribute__((ext_vector_type(4)));
typedef float  f32x4  __attribute__((ext_vector_type(4)));

// async global->LDS, 16B per lane. lds ptr must be wave-uniform base;
// HW writes base + lane*16 (m104/m108 semantics).
__device__ __forceinline__ void load16(const bf16_t* g, bf16_t* l) {
    __builtin_amdgcn_global_load_lds(
        (__attribute__((address_space(1))) void*)g,
        (__attribute__((address_space(3))) void*)l,
        16, 0, 0);
}

// ---------------- cast inp f32 -> bf16 (vectorized x4) ----------------
__global__ void cast_kernel(const float* __restrict__ src, bf16_t* __restrict__ dst, int n4) {
    int i = blockIdx.x * blockDim.x + threadIdx.x;
    if (i < n4) {
        float4 v = reinterpret_cast<const float4*>(src)[i];
        bf16x4 o;
        o[0] = (bf16_t)v.x; o[1] = (bf16_t)v.y; o[2] = (bf16_t)v.z; o[3] = (bf16_t)v.w;
        reinterpret_cast<bf16x4*>(dst)[i] = o;
    }
}

// ---------------- tiled transpose with zero padding ----------------
// src: K x N (f32, row-major).  dst: Npad x Kpad (bf16, row-major), pad = 0.
// Tile: 32 n-cols x 64 k-rows; writes are bf16x8 (16B) fully coalesced.
__global__ void transpose_pad(const float* __restrict__ W, bf16_t* __restrict__ WT,
                              int K, int N, int Kpad, int Npad) {
    __shared__ float tile[64][33];
    int n0 = blockIdx.x * 32, k0 = blockIdx.y * 64;
    int tx = threadIdx.x & 31, ty = threadIdx.x >> 5;   // 32 x 8
    #pragma unroll
    for (int i = 0; i < 8; i++) {
        int k = k0 + ty + i * 8, n = n0 + tx;
        tile[ty + i * 8][tx] = (k < K && n < N) ? W[(size_t)k * N + n] : 0.0f;
    }
    __syncthreads();
    int n = threadIdx.x >> 3, kc = threadIdx.x & 7;     // n 0..31, kc 0..7
    bf16x8 v;
    #pragma unroll
    for (int j = 0; j < 8; j++) v[j] = (bf16_t)tile[kc * 8 + j][n];
    *reinterpret_cast<bf16x8*>(WT + (size_t)(n0 + n) * Kpad + k0 + kc * 8) = v;
}

// ---------------- init: zero accumulators + out, precompute targets ----------------
__global__ void init_kernel(const int* __restrict__ labels, float* __restrict__ acc6,
                            int* __restrict__ tgts, float* __restrict__ out) {
    int t = blockIdx.x * blockDim.x + threadIdx.x;   // 4096 threads
    for (int j = t; j < 6 * M_TOK; j += M_TOK) acc6[j] = 0.0f;
    if (t == 0) out[0] = 0.0f;
    int lbl = labels[t];
    tgts[t]             = (lbl < 16000) ? lbl : ((lbl < 28000) ? 16000 : 16001);
    int t0 = lbl - 16000; t0 = t0 < 0 ? 0 : (t0 > 11999 ? 11999 : t0);
    int t1 = lbl - 28000; t1 = t1 < 0 ? 0 : (t1 > 7999  ? 7999  : t1);
    tgts[M_TOK + t]     = t0;
    tgts[2 * M_TOK + t] = t1;
}

// ---------------- MFMA GEMM: C = A(M x K) * BT(Npad x K)^T ----------------
// Block tile 128x128, BK=32, 4 waves 2x2, each wave 64x64 via 4x4 mfma_f32_16x16x32_bf16.
// Staging via global_load_lds width=16 (m97 structure).
template <bool LSE>
__launch_bounds__(256, 2)
__global__ void gemm_kernel(const bf16_t* __restrict__ A, const bf16_t* __restrict__ BT,
                            const float* __restrict__ bias, int K, int Npad, int realN,
                            const int* __restrict__ tgt, float* __restrict__ sumexp,
                            float* __restrict__ lab, bf16_t* __restrict__ out) {
    __shared__ __align__(16) bf16_t As[128][32];
    __shared__ __align__(16) bf16_t Bs[128][32];

    const int tid  = threadIdx.x;
    const int lane = tid & 63;
    const int wave = tid >> 6;
    const int wm = wave >> 1, wn = wave & 1;
    const int q = lane >> 4, lrow = lane & 15;
    const int m0 = blockIdx.x * 128, n0 = blockIdx.y * 128;

    f32x4 acc[4][4];
    #pragma unroll
    for (int mt = 0; mt < 4; mt++)
        #pragma unroll
        for (int nt = 0; nt < 4; nt++)
            acc[mt][nt] = (f32x4)(0.0f);

    for (int k0 = 0; k0 < K; k0 += 32) {
        #pragma unroll
        for (int p = 0; p < 2; p++) {
            int base_c = wave * 64 + p * 256;        // wave-uniform
            int c = base_c + lane;
            int row = c >> 2, ko = (c & 3) * 8;
            load16(A  + (size_t)(m0 + row) * K + k0 + ko, &As[0][0] + (size_t)base_c * 8);
            load16(BT + (size_t)(n0 + row) * K + k0 + ko, &Bs[0][0] + (size_t)base_c * 8);
        }
        __syncthreads();
        bf16x8 af[4], bfr[4];
        #pragma unroll
        for (int t = 0; t < 4; t++) {
            af[t]  = *reinterpret_cast<const bf16x8*>(&As[wm * 64 + t * 16 + lrow][q * 8]);
            bfr[t] = *reinterpret_cast<const bf16x8*>(&Bs[wn * 64 + t * 16 + lrow][q * 8]);
        }
        #pragma unroll
        for (int mt = 0; mt < 4; mt++)
            #pragma unroll
            for (int nt = 0; nt < 4; nt++)
                acc[mt][nt] = __builtin_amdgcn_mfma_f32_16x16x32_bf16(af[mt], bfr[nt], acc[mt][nt], 0, 0, 0);
        __syncthreads();
    }

    int colg[4]; float bias_v[4];
    #pragma unroll
    for (int nt = 0; nt < 4; nt++) {
        colg[nt] = n0 + wn * 64 + nt * 16 + lrow;
        bias_v[nt] = (colg[nt] < realN) ? bias[colg[nt]] : 0.0f;
    }

    if constexpr (LSE) {
        #pragma unroll
        for (int mt = 0; mt < 4; mt++) {
            int rowb = m0 + wm * 64 + mt * 16 + q * 4;
            #pragma unroll
            for (int r = 0; r < 4; r++) {
                int tok = rowb + r;
                int tg  = tgt[tok];
                float s = 0.0f;
                #pragma unroll
                for (int nt = 0; nt < 4; nt++) {
                    if (colg[nt] < realN) {
                        float logit = acc[mt][nt][r] + bias_v[nt];
                        s += __expf(logit);
                        if (colg[nt] == tg) atomicAdd(&lab[tok], logit);
                    }
                }
                s += __shfl_xor(s, 1);
                s += __shfl_xor(s, 2);
                s += __shfl_xor(s, 4);
                s += __shfl_xor(s, 8);
                if (lrow == 0) atomicAdd(&sumexp[tok], s);
            }
        }
    } else {
        #pragma unroll
        for (int mt = 0; mt < 4; mt++) {
            int rowb = m0 + wm * 64 + mt * 16 + q * 4;
            #pragma unroll
            for (int r = 0; r < 4; r++) {
                int tok = rowb + r;
                #pragma unroll
                for (int nt = 0; nt < 4; nt++)
                    out[(size_t)tok * Npad + colg[nt]] = (bf16_t)(acc[mt][nt][r] + bias_v[nt]);
            }
        }
    }
}

// ---------------- finalize: per-token loss, mask, mean ----------------
__global__ void finalize_kernel(const int* __restrict__ labels, const float* __restrict__ acc6,
                                float* __restrict__ out) {
    int t = blockIdx.x * blockDim.x + threadIdx.x;   // 4096 threads
    const float* sumH = acc6;
    const float* labH = acc6 + M_TOK;
    const float* sum0 = acc6 + 2 * M_TOK;
    const float* lab0 = acc6 + 3 * M_TOK;
    const float* sum1 = acc6 + 4 * M_TOK;
    const float* lab1 = acc6 + 5 * M_TOK;
    int lbl = labels[t];
    float l = 0.0f;
    if (lbl != 0) {
        l = logf(sumH[t]) - labH[t];
        if (lbl >= 16000 && lbl < 28000) l += logf(sum0[t]) - lab0[t];
        else if (lbl >= 28000)           l += logf(sum1[t]) - lab1[t];
    }
    l *= (1.0f / (float)M_TOK);
    #pragma unroll
    for (int off = 1; off < 64; off <<= 1) l += __shfl_xor(l, off);
    __shared__ float red[4];
    if ((threadIdx.x & 63) == 0) red[threadIdx.x >> 6] = l;
    __syncthreads();
    if (threadIdx.x == 0) atomicAdd(out, red[0] + red[1] + red[2] + red[3]);
}

// ---------------- host launcher ----------------
extern "C" void kernel_launch(void* const* d_in, const int* in_sizes, int n_in,
                              void* d_out, int out_size, void* d_ws, size_t ws_size,
                              hipStream_t stream) {
    const float* inp    = (const float*)d_in[0];
    const int*   labels = (const int*)  d_in[1];
    const float* head_W = (const float*)d_in[2];
    const float* head_b = (const float*)d_in[3];
    const float* t0_pW  = (const float*)d_in[4];
    const float* t0_pb  = (const float*)d_in[5];
    const float* t0_W   = (const float*)d_in[6];
    const float* t0_b   = (const float*)d_in[7];
    const float* t1_pW  = (const float*)d_in[8];
    const float* t1_pb  = (const float*)d_in[9];
    const float* t1_W   = (const float*)d_in[10];
    const float* t1_b   = (const float*)d_in[11];
    float* out = (float*)d_out;

    char* ws = (char*)d_ws;
    size_t off = 0;
    auto alloc = [&](size_t bytes) { char* p = ws + off; off += (bytes + 255) & ~(size_t)255; return p; };
    bf16_t* inp_bf = (bf16_t*)alloc((size_t)M_TOK * HID * 2);
    bf16_t* headWT = (bf16_t*)alloc((size_t)NHEAD_PAD * HID * 2);
    bf16_t* p0WT   = (bf16_t*)alloc((size_t)P0 * HID * 2);
    bf16_t* p1WT   = (bf16_t*)alloc((size_t)P1_PAD * HID * 2);
    bf16_t* t0WT   = (bf16_t*)alloc((size_t)N0_PAD * P0 * 2);
    bf16_t* t1WT   = (bf16_t*)alloc((size_t)N1_PAD * P1_PAD * 2);
    bf16_t* proj0  = (bf16_t*)alloc((size_t)M_TOK * P0 * 2);
    bf16_t* proj1  = (bf16_t*)alloc((size_t)M_TOK * P1_PAD * 2);
    float*  acc6   = (float*) alloc(6 * M_TOK * 4);
    int*    tgts   = (int*)   alloc(3 * M_TOK * 4);

    // stage 1: conversions / transposes
    cast_kernel<<<(M_TOK * HID / 4 + 255) / 256, 256, 0, stream>>>(inp, inp_bf, M_TOK * HID / 4);
    transpose_pad<<<dim3(NHEAD_PAD / 32, HID / 64),    256, 0, stream>>>(head_W, headWT, HID, NHEAD, HID,    NHEAD_PAD);
    transpose_pad<<<dim3(P0 / 32,        HID / 64),    256, 0, stream>>>(t0_pW,  p0WT,   HID, P0,    HID,    P0);
    transpose_pad<<<dim3(P1_PAD / 32,    HID / 64),    256, 0, stream>>>(t1_pW,  p1WT,   HID, P1,    HID,    P1_PAD);
    transpose_pad<<<dim3(N0_PAD / 32,    P0 / 64),     256, 0, stream>>>(t0_W,   t0WT,   P0,  N0,    P0,     N0_PAD);
    transpose_pad<<<dim3(N1_PAD / 32,    P1_PAD / 64), 256, 0, stream>>>(t1_W,   t1WT,   P1,  N1,    P1_PAD, N1_PAD);
    init_kernel<<<M_TOK / 256, 256, 0, stream>>>(labels, acc6, tgts, out);

    // stage 2: tail projections (store epilogue)
    gemm_kernel<false><<<dim3(M_TOK / 128, P0 / 128),     256, 0, stream>>>(inp_bf, p0WT, t0_pb, HID, P0,     P0, nullptr, nullptr, nullptr, proj0);
    gemm_kernel<false><<<dim3(M_TOK / 128, P1_PAD / 128), 256, 0, stream>>>(inp_bf, p1WT, t1_pb, HID, P1_PAD, P1, nullptr, nullptr, nullptr, proj1);

    // stage 3: logsumexp GEMMs (head + tails)
    gemm_kernel<true><<<dim3(M_TOK / 128, NHEAD_PAD / 128), 256, 0, stream>>>(inp_bf, headWT, head_b, HID,    NHEAD_PAD, NHEAD, tgts,             acc6,             acc6 + M_TOK,     nullptr);
    gemm_kernel<true><<<dim3(M_TOK / 128, N0_PAD / 128),    256, 0, stream>>>(proj0,  t0WT,   t0_b,   P0,     N0_PAD,    N0,    tgts + M_TOK,     acc6 + 2 * M_TOK, acc6 + 3 * M_TOK, nullptr);
    gemm_kernel<true><<<dim3(M_TOK / 128, N1_PAD / 128),    256, 0, stream>>>(proj1,  t1WT,   t1_b,   P1_PAD, N1_PAD,    N1,    tgts + 2 * M_TOK, acc6 + 4 * M_TOK, acc6 + 5 * M_TOK, nullptr);

    // stage 4: reduce to scalar mean
    finalize_kernel<<<M_TOK / 256, 256, 0, stream>>>(labels, acc6, out);
}